// Round 3
// baseline (537.119 us; speedup 1.0000x reference)
//
#include <hip/hip_runtime.h>

#define B_ 16
#define C_ 512
#define S_ 4096

typedef __attribute__((ext_vector_type(4))) float float4v;
typedef __attribute__((ext_vector_type(8))) short short8;
typedef __attribute__((ext_vector_type(4))) short short4v;

typedef __attribute__((address_space(1))) unsigned int as1_uint;
typedef __attribute__((address_space(3))) unsigned int as3_uint;

// async global->LDS, 16 bytes per lane (emits global_load_lds_dwordx4)
#define ASYNC16(gsrc, ldst) \
  __builtin_amdgcn_global_load_lds((as1_uint*)(gsrc), (as3_uint*)(ldst), 16, 0, 0)

// counted-vmcnt pipeline sync: wait until <=N vmem ops outstanding, barrier.
#define PIPE_SYNC(N)                                                   \
  do {                                                                 \
    asm volatile("s_waitcnt vmcnt(" #N ")\n\ts_barrier" ::: "memory"); \
    __builtin_amdgcn_sched_barrier(0);                                 \
  } while (0)

__device__ __forceinline__ unsigned short f2bf(float f) {
  unsigned u = __builtin_bit_cast(unsigned, f);
  u = u + 0x7FFFu + ((u >> 16) & 1u);  // round-to-nearest-even
  return (unsigned short)(u >> 16);
}

// ---------------- kernel 1a: pure streaming f32 -> bf16 convert -------------
// No LDS, no barrier: blocks [0,2048) convert depth, [2048,4096) convert rgb.
__global__ __launch_bounds__(256) void k_conv(
    const float* __restrict__ depth, const float* __restrict__ rgb,
    unsigned short* __restrict__ depthN, unsigned short* __restrict__ rgbN) {
  int half = blockIdx.x >> 11;
  const float* src = half ? rgb : depth;
  unsigned short* dst = half ? rgbN : depthN;
  size_t tid = ((size_t)(blockIdx.x & 2047)) * 256 + threadIdx.x;
#pragma unroll
  for (int it = 0; it < 8; ++it) {
    size_t c = tid + (size_t)it * 524288;  // chunk of 8 floats
    const float* p = src + c * 8;
    float4v v0 = *(const float4v*)p;
    float4v v1 = *(const float4v*)(p + 4);
    short8 o = {(short)f2bf(v0.x), (short)f2bf(v0.y), (short)f2bf(v0.z),
                (short)f2bf(v0.w), (short)f2bf(v1.x), (short)f2bf(v1.y),
                (short)f2bf(v1.z), (short)f2bf(v1.w)};
    *(short8*)(dst + c * 8) = o;
  }
}

// ---------------- kernel 1b: bf16 transpose depthN -> depthT ----------------
// 64(s) x 64(d) tile. Phase 1: short8 loads, vector 8B LDS writes ([d][68]
// stride: 8*136B = 1088 % 128 != 0 so phase-2 column gathers are <=8-way).
// Phase 2: 8 scalar u16 gathers + one 16B coalesced store per slot.
__global__ __launch_bounds__(256) void k_trans(
    const unsigned short* __restrict__ depthN,
    unsigned short* __restrict__ depthT) {
  __shared__ __align__(16) unsigned short tT[64][68];
  int b = blockIdx.z;
  int s0 = blockIdx.x * 64, d0 = blockIdx.y * 64;
  int t = threadIdx.x;
  const unsigned short* src = depthN + ((size_t)(b * C_ + d0)) * S_ + s0;
#pragma unroll
  for (int it = 0; it < 2; ++it) {
    int slot = it * 256 + t;
    int d = slot >> 3, c = slot & 7;
    short8 v = *(const short8*)(src + (size_t)d * S_ + c * 8);
    short4v lo = {v[0], v[1], v[2], v[3]};
    short4v hi = {v[4], v[5], v[6], v[7]};
    *(short4v*)&tT[d][c * 8] = lo;
    *(short4v*)&tT[d][c * 8 + 4] = hi;
  }
  __syncthreads();
  unsigned short* dst = depthT + ((size_t)(b * S_ + s0)) * C_ + d0;
#pragma unroll
  for (int it = 0; it < 2; ++it) {
    int slot = it * 256 + t;
    int s = slot >> 3, g = slot & 7;
    short8 o;
#pragma unroll
    for (int e = 0; e < 8; ++e) o[e] = (short)tT[g * 8 + e][s];
    *(short8*)(dst + (size_t)s * C_ + g * 8) = o;  // 16B/lane coalesced
  }
}

// ---------------- kernel 2: gemm1 + fused sigmoid ---------------------------
// I[b][c][d] = bf16(sigmoid( sum_s depthN[c,s]*rgbN[d,s] ))
// 128x128 tile, BK=64, grid 256 (1 block/CU), triple-buffered counted vmcnt.
// XCD-chunked swizzle: each XCD owns 2 batches -> K-windows stay L2-resident.
__global__ __launch_bounds__(256) void k_gemm1(
    const unsigned short* __restrict__ depthN,
    const unsigned short* __restrict__ rgbN, unsigned short* __restrict__ I) {
  __shared__ __align__(16) short As[3][128 * 64];  // 16 KiB each
  __shared__ __align__(16) short Bs[3][128 * 64];
  int lid = blockIdx.x + 4 * blockIdx.y + 16 * blockIdx.z;  // 256 wgs
  int swz = (lid & 7) * 32 + (lid >> 3);
  int bx = swz & 3, by = (swz >> 2) & 3, b = swz >> 4;
  int c0 = bx * 128, d0 = by * 128;
  int t = threadIdx.x;
  const unsigned short* An = depthN + ((size_t)(b * C_ + c0)) * S_;
  const unsigned short* Bn = rgbN + ((size_t)(b * C_ + d0)) * S_;
  int w = t >> 6, l = t & 63, half = l >> 4, r = l & 15;
  int wm = (w >> 1) * 64, wn = (w & 1) * 64;  // wave tile 64x64
  float4v acc[4][4] = {};

  auto stage = [&](int bi, int k0) {
#pragma unroll
    for (int q = 0; q < 4; ++q) {
      int idx = q * 256 + t, row = idx >> 3, ch = (idx & 7) ^ (row & 7);
      ASYNC16(An + (size_t)row * S_ + k0 + ch * 8, &As[bi][idx * 8]);
    }
#pragma unroll
    for (int q = 0; q < 4; ++q) {
      int idx = q * 256 + t, row = idx >> 3, ch = (idx & 7) ^ (row & 7);
      ASYNC16(Bn + (size_t)row * S_ + k0 + ch * 8, &Bs[bi][idx * 8]);
    }
  };

  stage(0, 0);
  stage(1, 64);
  stage(2, 128);
  PIPE_SYNC(16);  // tile 0 landed (16 = tiles 1,2 in flight)

  const int NKT = S_ / 64;  // 64
  for (int kt = 0; kt < NKT; ++kt) {
    int cur = kt % 3;
    short8 af[4][2], bfr[4][2];
#pragma unroll
    for (int i = 0; i < 4; ++i) {
      int row = wm + 16 * i + r;
#pragma unroll
      for (int kk = 0; kk < 2; ++kk)
        af[i][kk] = *(const short8*)&As[cur][row * 64 +
                                            (((kk * 4 + half) ^ (row & 7)) * 8)];
    }
#pragma unroll
    for (int j = 0; j < 4; ++j) {
      int row = wn + 16 * j + r;
#pragma unroll
      for (int kk = 0; kk < 2; ++kk)
        bfr[j][kk] = *(const short8*)&Bs[cur][row * 64 +
                                             (((kk * 4 + half) ^ (row & 7)) * 8)];
    }
    __builtin_amdgcn_s_setprio(1);
#pragma unroll
    for (int kk = 0; kk < 2; ++kk)
#pragma unroll
      for (int i = 0; i < 4; ++i)
#pragma unroll
        for (int j = 0; j < 4; ++j)
          acc[i][j] = __builtin_amdgcn_mfma_f32_16x16x32_bf16(
              af[i][kk], bfr[j][kk], acc[i][j], 0, 0, 0);
    __builtin_amdgcn_s_setprio(0);
    if (kt + 2 < NKT) {
      PIPE_SYNC(8);  // tile kt+1 landed; kt+2 (8 loads) stays in flight
    } else if (kt + 1 < NKT) {
      PIPE_SYNC(0);
    }
    if (kt + 3 < NKT) stage(cur, (kt + 3) * 64);
  }

  // sigmoid -> bf16. C/D layout: col(d)=lane&15, row(c)=(lane>>4)*4+reg
#pragma unroll
  for (int i = 0; i < 4; ++i)
#pragma unroll
    for (int j = 0; j < 4; ++j)
#pragma unroll
      for (int reg = 0; reg < 4; ++reg) {
        int c = c0 + wm + 16 * i + half * 4 + reg;
        int d = d0 + wn + 16 * j + r;
        float g = 1.0f / (1.0f + __expf(-acc[i][j][reg]));
        I[((size_t)(b * C_ + c)) * C_ + d] = f2bf(g);
      }
}

// ---------------- kernel 3: gemm2 + epilogue add ----------------------------
// out[b][c][s] = rgb[b][c][s] + sum_d I[c,d]*depthT[s,d]
// 256(c) x 64(s) tile, BK=32, grid 2048 (2 blocks/CU), triple-buffered.
// depthT refetched only 2x (C/256); I panels L2-resident (512 KB/batch).
__global__ __launch_bounds__(256) void k_gemm2(
    const unsigned short* __restrict__ I,
    const unsigned short* __restrict__ depthT, const float* __restrict__ rgb,
    float* __restrict__ out) {
  __shared__ __align__(16) short As[3][256 * 32];  // 16 KiB each
  __shared__ __align__(16) short Bs[3][64 * 32];   // 4 KiB each
  int lid = blockIdx.x + 2 * blockIdx.y + 128 * blockIdx.z;  // 2048 wgs
  int swz = (lid & 7) * 256 + (lid >> 3);
  int bx = swz & 1, by = (swz >> 1) & 63, b = swz >> 7;
  int c0 = bx * 256, s0 = by * 64;
  int t = threadIdx.x;
  const unsigned short* Ab = I + ((size_t)(b * C_ + c0)) * C_;
  const unsigned short* Bb = depthT + ((size_t)(b * S_ + s0)) * C_;
  int w = t >> 6, l = t & 63, half = l >> 4, r = l & 15;
  int wm = w * 64, wn = 0;  // wave tile 64x64 (4 waves stacked on c)
  float4v acc[4][4] = {};

  auto stage = [&](int bi, int k0) {
#pragma unroll
    for (int q = 0; q < 4; ++q) {
      int idx = q * 256 + t, row = idx >> 2, ch = (idx & 3) ^ (row & 3);
      ASYNC16(Ab + (size_t)row * C_ + k0 + ch * 8, &As[bi][idx * 8]);
    }
    {
      int idx = t, row = idx >> 2, ch = (idx & 3) ^ (row & 3);
      ASYNC16(Bb + (size_t)row * C_ + k0 + ch * 8, &Bs[bi][idx * 8]);
    }
  };

  stage(0, 0);
  stage(1, 32);
  stage(2, 64);
  PIPE_SYNC(10);  // tile 0 landed (10 = tiles 1,2 in flight)

  const int NKT = C_ / 32;  // 16
  for (int kt = 0; kt < NKT; ++kt) {
    int cur = kt % 3;
    short8 af[4], bfr[4];
#pragma unroll
    for (int i = 0; i < 4; ++i) {
      int rowa = wm + 16 * i + r;
      af[i] =
          *(const short8*)&As[cur][rowa * 32 + (((half ^ (rowa & 3)) & 3) * 8)];
      int rowb = wn + 16 * i + r;
      bfr[i] =
          *(const short8*)&Bs[cur][rowb * 32 + (((half ^ (rowb & 3)) & 3) * 8)];
    }
    __builtin_amdgcn_s_setprio(1);
#pragma unroll
    for (int i = 0; i < 4; ++i)
#pragma unroll
      for (int j = 0; j < 4; ++j)
        acc[i][j] = __builtin_amdgcn_mfma_f32_16x16x32_bf16(af[i], bfr[j],
                                                            acc[i][j], 0, 0, 0);
    __builtin_amdgcn_s_setprio(0);
    if (kt + 2 < NKT) {
      PIPE_SYNC(5);
    } else if (kt + 1 < NKT) {
      PIPE_SYNC(0);
    }
    if (kt + 3 < NKT) stage(cur, (kt + 3) * 32);
  }

#pragma unroll
  for (int i = 0; i < 4; ++i)
#pragma unroll
    for (int j = 0; j < 4; ++j)
#pragma unroll
      for (int reg = 0; reg < 4; ++reg) {
        int c = c0 + wm + 16 * i + half * 4 + reg;
        int s = s0 + wn + 16 * j + r;
        size_t o = ((size_t)(b * C_ + c)) * S_ + s;
        out[o] = rgb[o] + acc[i][j][reg];
      }
}

extern "C" void kernel_launch(void* const* d_in, const int* in_sizes, int n_in,
                              void* d_out, int out_size, void* d_ws,
                              size_t ws_size, hipStream_t stream) {
  const float* rgb = (const float*)d_in[0];    // rgb_feat
  const float* depth = (const float*)d_in[1];  // depth_feat
  float* out = (float*)d_out;
  // ws (72 MiB): depthT bf16 (64 MiB) | I bf16 (8 MiB)
  unsigned short* depthT = (unsigned short*)d_ws;
  unsigned short* I = (unsigned short*)((char*)d_ws + (size_t)B_ * S_ * C_ * 2);
  // d_out doubles as scratch: [0,64MiB)=depthN, [64,128MiB)=rgbN; consumed by
  // k_trans/k_gemm1 before k_gemm2 overwrites d_out with the final result.
  unsigned short* depthN = (unsigned short*)d_out;
  unsigned short* rgbN = depthN + (size_t)B_ * C_ * S_;

  k_conv<<<dim3(4096), 256, 0, stream>>>(depth, rgb, depthN, rgbN);
  k_trans<<<dim3(S_ / 64, C_ / 64, B_), 256, 0, stream>>>(depthN, depthT);
  k_gemm1<<<dim3(C_ / 128, C_ / 128, B_), 256, 0, stream>>>(depthN, rgbN, I);
  k_gemm2<<<dim3(C_ / 256, S_ / 64, B_), 256, 0, stream>>>(I, depthT, rgb, out);
}